// Round 1
// baseline (2035.847 us; speedup 1.0000x reference)
//
#include <hip/hip_runtime.h>
#include <hip/hip_bf16.h>

// Problem constants (from reference)
#define NND   20000
#define TSTEP 64
#define FF    128
#define BB    8192
#define KK    32
#define QQ    (3*BB)      // 24576
#define WWINC 64
#define DDIM  16
#define MDIM  64          // msg dim
#define HDIM  128         // hidden dim
#define HHDIM 64          // h dim
#define CATW  144         // F + DD
#define CATP  148         // padded LDS row stride (148%32=20 -> conflict-free across 8 k's)

// 8-wide FMA helper: acc[0..7] += cc * base[0..7]
#define FMA8(cc, base) do { \
    const float4 wa_ = *(const float4*)(base); \
    const float4 wb_ = *(const float4*)((base) + 4); \
    acc[0] = fmaf((cc), wa_.x, acc[0]); acc[1] = fmaf((cc), wa_.y, acc[1]); \
    acc[2] = fmaf((cc), wa_.z, acc[2]); acc[3] = fmaf((cc), wa_.w, acc[3]); \
    acc[4] = fmaf((cc), wb_.x, acc[4]); acc[5] = fmaf((cc), wb_.y, acc[5]); \
    acc[6] = fmaf((cc), wb_.z, acc[6]); acc[7] = fmaf((cc), wb_.w, acc[7]); \
  } while (0)

// ---------------------------------------------------------------------------
// Kernel 1: edge aggregation (called twice: sign=+1 with piw*, sign=-1 with pow*)
// One q per block iteration. LDS: W1(36.9K)+W2(16.4K)+cat(18.9K)+misc = 73.2KB
// -> 2 blocks/CU.
// ---------------------------------------------------------------------------
__global__ __launch_bounds__(256, 2)
void agg_kernel(const float* __restrict__ x, const float* __restrict__ demb,
                const float* __restrict__ w1, const float* __restrict__ b1,
                const float* __restrict__ w2, const float* __restrict__ b2,
                const int* __restrict__ times, const int* __restrict__ uu,
                const int* __restrict__ tt, const int* __restrict__ mm,
                float* __restrict__ mout, const int sign)
{
    __shared__ float w1s[CATW * MDIM];
    __shared__ float w2s[MDIM * MDIM];
    __shared__ float b1s[MDIM];
    __shared__ float b2s[MDIM];
    __shared__ float cat[KK * CATP];   // cat rows; reused for hidden, then msg
    __shared__ float mskf[KK];
    __shared__ int   ubase[KK];
    __shared__ int   dbase[KK];
    __shared__ int   mski[KK];
    __shared__ float cntinv;

    const int tid = threadIdx.x;

    // Stage weights once per block
    for (int i = tid; i < CATW * MDIM; i += 256) w1s[i] = w1[i];
    for (int i = tid; i < MDIM * MDIM; i += 256) w2s[i] = w2[i];
    if (tid < MDIM) { b1s[tid] = b1[tid]; b2s[tid] = b2[tid]; }
    __syncthreads();

    const int k   = tid >> 3;     // neighbor row 0..31 (8 threads each)
    const int jg8 = (tid & 7) * 8; // output column group base

    for (int q = blockIdx.x; q < QQ; q += gridDim.x) {
        const int t = times[q];
        if (tid < KK) {
            const int u   = uu[q * KK + tid];
            const int tau = tt[q * KK + tid];
            const int m   = mm[q * KK + tid];
            int d = (sign > 0) ? (t - tau) : (tau - t);
            d = d < 0 ? 0 : (d > WWINC ? WWINC : d);
            ubase[tid] = u * (TSTEP * FF) + tau * FF;
            dbase[tid] = d * DDIM;
            mski[tid]  = m;
            mskf[tid]  = m ? 1.0f : 0.0f;
        }
        __syncthreads();
        if (tid == 0) {
            float s = 0.0f;
            for (int i = 0; i < KK; i++) s += mskf[i];
            cntinv = 1.0f / fmaxf(s, 1.0f);
        }
        // Stage cat = [x_u(128) | delta_emb(16)] per neighbor; zero if masked
        // (masked rows compute garbage-free zeros-in; masked out at the mean)
        for (int e = tid; e < KK * 36; e += 256) {
            const int kr = e / 36;
            const int c  = e - kr * 36;
            float4 v = make_float4(0.f, 0.f, 0.f, 0.f);
            if (mski[kr]) {
                if (c < 32) v = *(const float4*)(x + ubase[kr] + c * 4);
                else        v = *(const float4*)(demb + dbase[kr] + (c - 32) * 4);
            }
            *(float4*)(cat + kr * CATP + c * 4) = v;
        }
        __syncthreads();

        // GEMM1: hidden[k][j] = relu(sum_i cat[k][i]*W1[i][j] + b1[j])
        float acc[8];
        {
            const float* crow = cat + k * CATP;
            #pragma unroll
            for (int r = 0; r < 8; r++) acc[r] = b1s[jg8 + r];
            #pragma unroll 4
            for (int i = 0; i < CATW; i++) {
                const float cc = crow[i];
                FMA8(cc, w1s + i * MDIM + jg8);
            }
            #pragma unroll
            for (int r = 0; r < 8; r++) acc[r] = fmaxf(acc[r], 0.0f);
        }
        __syncthreads();  // everyone done reading cat
        *(float4*)(cat + k * CATP + jg8)     = make_float4(acc[0], acc[1], acc[2], acc[3]);
        *(float4*)(cat + k * CATP + jg8 + 4) = make_float4(acc[4], acc[5], acc[6], acc[7]);
        __syncthreads();  // hidden ready

        // GEMM2: msg[k][j] = (sum_i hid[k][i]*W2[i][j] + b2[j]) * mask[k]
        {
            const float* hrow = cat + k * CATP;
            #pragma unroll
            for (int r = 0; r < 8; r++) acc[r] = b2s[jg8 + r];
            #pragma unroll 4
            for (int i = 0; i < MDIM; i++) {
                const float hh = hrow[i];
                FMA8(hh, w2s + i * MDIM + jg8);
            }
            const float mk = mskf[k];
            #pragma unroll
            for (int r = 0; r < 8; r++) acc[r] *= mk;
        }
        __syncthreads();  // everyone done reading hidden
        *(float4*)(cat + k * CATP + jg8)     = make_float4(acc[0], acc[1], acc[2], acc[3]);
        *(float4*)(cat + k * CATP + jg8 + 4) = make_float4(acc[4], acc[5], acc[6], acc[7]);
        __syncthreads();  // masked msg ready

        // Masked mean over k -> mout[q][0..63]
        if (tid < MDIM) {
            float s = 0.0f;
            #pragma unroll 4
            for (int kr = 0; kr < KK; kr++) s += cat[kr * CATP + tid];
            mout[(size_t)q * MDIM + tid] = s * cntinv;
        }
        __syncthreads();  // protect cat/meta/cntinv before next q
    }
}

// ---------------------------------------------------------------------------
// Kernel 2: combine. h[q] = relu( relu([xvt|m_in|m_out] @ cw1 + cb1) @ cw2 + cb2 )
// 16 q per block iteration. cw1 read from global (coalesced 512B rows, L2-hot);
// cw2 staged in LDS. LDS ~58.7KB -> 2 blocks/CU.
// ---------------------------------------------------------------------------
#define G2 16
#define FEATP 260   // 256 padded: (260*g+i)%32 distinct across g in a wave
#define H1P   132   // 128 padded

__global__ __launch_bounds__(256, 2)
void combine_kernel(const float* __restrict__ x,
                    const float* __restrict__ cw1, const float* __restrict__ cb1,
                    const float* __restrict__ cw2, const float* __restrict__ cb2,
                    const int* __restrict__ node_ids, const int* __restrict__ times,
                    const float* __restrict__ min_ws, const float* __restrict__ mout_ws,
                    float* __restrict__ h_ws)
{
    __shared__ float feat[G2 * FEATP];
    __shared__ float h1b[G2 * H1P];
    __shared__ float cw2s[HDIM * HHDIM];
    __shared__ float cb1s[HDIM];
    __shared__ float cb2s[HHDIM];
    __shared__ int   xb[G2];

    const int tid = threadIdx.x;
    for (int i = tid; i < HDIM * HHDIM; i += 256) cw2s[i] = cw2[i];
    if (tid < HDIM)  cb1s[tid] = cb1[tid];
    if (tid < HHDIM) cb2s[tid] = cb2[tid];
    __syncthreads();

    const int g = tid >> 4;   // 0..15 (q within group)
    const int j = tid & 15;   // 0..15 (column group)

    for (int qb = blockIdx.x * G2; qb < QQ; qb += gridDim.x * G2) {
        if (tid < G2) xb[tid] = node_ids[qb + tid] * (TSTEP * FF) + times[qb + tid] * FF;
        __syncthreads();
        // Stage feat = [x_vt(128) | m_in(64) | m_out(64)]
        for (int e = tid; e < G2 * 64; e += 256) {
            const int gg = e >> 6, c = e & 63;
            const int q = qb + gg;
            float4 v;
            if (c < 32)      v = *(const float4*)(x + xb[gg] + c * 4);
            else if (c < 48) v = *(const float4*)(min_ws  + (size_t)q * MDIM + (c - 32) * 4);
            else             v = *(const float4*)(mout_ws + (size_t)q * MDIM + (c - 48) * 4);
            *(float4*)(feat + gg * FEATP + c * 4) = v;
        }
        __syncthreads();

        // Layer 1: 128 outputs, thread covers 8 columns
        float acc[8];
        {
            const float* fr = feat + g * FEATP;
            #pragma unroll
            for (int r = 0; r < 8; r++) acc[r] = cb1s[j * 8 + r];
            #pragma unroll 4
            for (int i = 0; i < 2 * HDIM; i++) {
                const float f = fr[i];
                FMA8(f, cw1 + i * HDIM + j * 8);  // global, 512B coalesced row/wave
            }
            #pragma unroll
            for (int r = 0; r < 8; r++) acc[r] = fmaxf(acc[r], 0.0f);
        }
        *(float4*)(h1b + g * H1P + j * 8)     = make_float4(acc[0], acc[1], acc[2], acc[3]);
        *(float4*)(h1b + g * H1P + j * 8 + 4) = make_float4(acc[4], acc[5], acc[6], acc[7]);
        __syncthreads();

        // Layer 2: 64 outputs, thread covers 4 columns; outer relu; write h_ws
        {
            float a2[4];
            #pragma unroll
            for (int r = 0; r < 4; r++) a2[r] = cb2s[j * 4 + r];
            const float* hr = h1b + g * H1P;
            #pragma unroll 4
            for (int i = 0; i < HDIM; i++) {
                const float hh = hr[i];
                const float4 w = *(const float4*)(cw2s + i * HHDIM + j * 4);
                a2[0] = fmaf(hh, w.x, a2[0]); a2[1] = fmaf(hh, w.y, a2[1]);
                a2[2] = fmaf(hh, w.z, a2[2]); a2[3] = fmaf(hh, w.w, a2[3]);
            }
            #pragma unroll
            for (int r = 0; r < 4; r++) a2[r] = fmaxf(a2[r], 0.0f);
            *(float4*)(h_ws + (size_t)(qb + g) * HHDIM + j * 4) =
                make_float4(a2[0], a2[1], a2[2], a2[3]);
        }
        __syncthreads();
    }
}

// ---------------------------------------------------------------------------
// Kernel 3: scorer. out[b] = relu([h3b|h3b1|h3b2|d_norm] @ sw1 + sb1) @ sw2 + sb2
// 8 b per block iteration; layer2 dot in registers + shfl reduction.
// ---------------------------------------------------------------------------
#define G3 8
#define SFP 200   // 193 padded

__global__ __launch_bounds__(256, 2)
void score_kernel(const float* __restrict__ h_ws, const float* __restrict__ dnorm,
                  const float* __restrict__ sw1, const float* __restrict__ sb1,
                  const float* __restrict__ sw2, const float* __restrict__ sb2,
                  float* __restrict__ out)
{
    __shared__ float featb[G3 * SFP];
    __shared__ float sw2s[HDIM];
    __shared__ float sb1s[HDIM];

    const int tid = threadIdx.x;
    if (tid < HDIM) { sw2s[tid] = sw2[tid]; sb1s[tid] = sb1[tid]; }
    __syncthreads();

    const int g = tid >> 5;   // 0..7
    const int j = tid & 31;   // 0..31

    for (int bb = blockIdx.x * G3; bb < BB; bb += gridDim.x * G3) {
        // Stage feat: h rows 3b..3b+2 are 192 contiguous floats in h_ws
        for (int e = tid; e < G3 * 48; e += 256) {
            const int gg = e / 48, c = e - gg * 48;
            *(float4*)(featb + gg * SFP + c * 4) =
                *(const float4*)(h_ws + (size_t)(bb + gg) * 192 + c * 4);
        }
        if (tid < G3) featb[tid * SFP + 192] = dnorm[bb + tid];
        __syncthreads();

        // Layer 1 (193 -> 128), thread covers 4 columns
        float a[4];
        #pragma unroll
        for (int r = 0; r < 4; r++) a[r] = sb1s[j * 4 + r];
        const float* fr = featb + g * SFP;
        for (int i = 0; i < 193; i++) {
            const float f = fr[i];
            const float4 w = *(const float4*)(sw1 + i * HDIM + j * 4);
            a[0] = fmaf(f, w.x, a[0]); a[1] = fmaf(f, w.y, a[1]);
            a[2] = fmaf(f, w.z, a[2]); a[3] = fmaf(f, w.w, a[3]);
        }
        // relu + partial dot with sw2, reduce across the 32-lane subgroup
        float p = 0.0f;
        #pragma unroll
        for (int r = 0; r < 4; r++) p += fmaxf(a[r], 0.0f) * sw2s[j * 4 + r];
        for (int off = 16; off > 0; off >>= 1) p += __shfl_down(p, off, 32);
        if (j == 0) out[bb + g] = p + sb2[0];
        __syncthreads();
    }
}

// ---------------------------------------------------------------------------
extern "C" void kernel_launch(void* const* d_in, const int* in_sizes, int n_in,
                              void* d_out, int out_size, void* d_ws, size_t ws_size,
                              hipStream_t stream)
{
    const float* x     = (const float*)d_in[0];
    const float* dnorm = (const float*)d_in[1];
    const float* demb  = (const float*)d_in[2];
    const float* piw1  = (const float*)d_in[3];
    const float* pib1  = (const float*)d_in[4];
    const float* piw2  = (const float*)d_in[5];
    const float* pib2  = (const float*)d_in[6];
    const float* pow1  = (const float*)d_in[7];
    const float* pob1  = (const float*)d_in[8];
    const float* pow2  = (const float*)d_in[9];
    const float* pob2  = (const float*)d_in[10];
    const float* cw1   = (const float*)d_in[11];
    const float* cb1   = (const float*)d_in[12];
    const float* cw2   = (const float*)d_in[13];
    const float* cb2   = (const float*)d_in[14];
    const float* sw1   = (const float*)d_in[15];
    const float* sb1   = (const float*)d_in[16];
    const float* sw2   = (const float*)d_in[17];
    const float* sb2   = (const float*)d_in[18];
    const int* node_ids = (const int*)d_in[19];
    const int* times    = (const int*)d_in[20];
    const int* in_u     = (const int*)d_in[21];
    const int* in_tau   = (const int*)d_in[22];
    const int* in_mask  = (const int*)d_in[23];
    const int* out_u    = (const int*)d_in[24];
    const int* out_tau  = (const int*)d_in[25];
    const int* out_mask = (const int*)d_in[26];

    float* ws      = (float*)d_ws;
    float* min_ws  = ws;                       // QQ*64 floats
    float* mout_ws = ws + (size_t)QQ * MDIM;   // QQ*64 floats
    float* h_ws    = ws + (size_t)2 * QQ * MDIM; // QQ*64 floats
    float* out     = (float*)d_out;

    agg_kernel<<<512, 256, 0, stream>>>(x, demb, piw1, pib1, piw2, pib2,
                                        times, in_u, in_tau, in_mask, min_ws, 1);
    agg_kernel<<<512, 256, 0, stream>>>(x, demb, pow1, pob1, pow2, pob2,
                                        times, out_u, out_tau, out_mask, mout_ws, -1);
    combine_kernel<<<512, 256, 0, stream>>>(x, cw1, cb1, cw2, cb2,
                                            node_ids, times, min_ws, mout_ws, h_ws);
    score_kernel<<<256, 256, 0, stream>>>(h_ws, dnorm, sw1, sb1, sw2, sb2, out);
}

// Round 2
// 1028.398 us; speedup vs baseline: 1.9796x; 1.9796x over previous
//
#include <hip/hip_runtime.h>
#include <hip/hip_bf16.h>

// Problem constants (from reference)
#define NND   20000
#define TSTEP 64
#define FF    128
#define BB    8192
#define KK    32
#define QQ    (3*BB)      // 24576
#define WWINC 64
#define DDIM  16
#define MDIM  64          // msg dim
#define HDIM  128         // hidden dim
#define HHDIM 64          // h dim

typedef __attribute__((ext_vector_type(8)))  short short8;   // 8 bf16 (4 VGPRs)
typedef __attribute__((ext_vector_type(16))) float f32x16;   // 32x32 MFMA acc

union FragU { unsigned u[4]; short8 s; };

// fp32 -> bf16 (RNE), packed pair -> one dword
static __device__ __forceinline__ unsigned pkbf(float a, float b) {
    union { float f; unsigned u; } ua, ub; ua.f = a; ub.f = b;
    unsigned ra = (ua.u + 0x7FFFu + ((ua.u >> 16) & 1u)) >> 16;
    unsigned rb = (ub.u + 0x7FFFu + ((ub.u >> 16) & 1u)) >> 16;
    return (ra & 0xFFFFu) | (rb << 16);
}
static __device__ __forceinline__ unsigned short f2bf(float a) {
    union { float f; unsigned u; } v; v.f = a;
    return (unsigned short)((v.u + 0x7FFFu + ((v.u >> 16) & 1u)) >> 16);
}

// ---------------------------------------------------------------------------
// MFMA edge aggregation. One q per WAVE (no block barriers in the q loop).
// GEMM1: cat[32x144] @ W1[144x64]  (9 K-steps of 32x32x16, 2 N-tiles)
//   A gathered straight from global into fragment regs (row = lane&31,
//   k-half = lane>>5); masked rows zeroed via exec mask.
// GEMM2: relu(H)[32x64] @ W2[64x64] (H via per-wave LDS; W2 frags in VGPRs)
// Mask/mean: masked rows zeroed at H-write; mean = sum*cinv + b2*has.
// LDS: w1frag 18KB + H 18KB -> 3 blocks/CU with __launch_bounds__(256,3).
// ---------------------------------------------------------------------------
#define NW  4     // waves per block
#define HLD 72    // H row stride in bf16 (4-way-minimum b128 reads)

__global__ __launch_bounds__(256, 3)
void agg_mfma_kernel(const float* __restrict__ x, const float* __restrict__ demb,
                     const float* __restrict__ w1, const float* __restrict__ b1,
                     const float* __restrict__ w2, const float* __restrict__ b2,
                     const int* __restrict__ times, const int* __restrict__ uu,
                     const int* __restrict__ tt, const int* __restrict__ mm,
                     float* __restrict__ mout, const int sign, const int nwaves)
{
    __shared__ short w1f[9 * 2 * 64 * 8];        // W1 in B-fragment order, 18432 B
    __shared__ short Hs[NW][KK * HLD];           // per-wave hidden, 18432 B

    const int tid  = threadIdx.x;
    const int lane = tid & 63;
    const int wv   = tid >> 6;
    const int r    = lane & 31;   // edge row (GEMM1 A / GEMM2 A), col (C/D)
    const int hi   = lane >> 5;   // k-half selector

    // ---- one-time: stage W1 fragments to LDS ----
    // frag f = (s*2+n)*64 + ln holds B[k=16s+8*(ln>>5)+i][col=32n+(ln&31)], i=0..7
    for (int f = tid; f < 9 * 2 * 64; f += 256) {
        const int ln = f & 63, sn = f >> 6, s = sn >> 1, n = sn & 1;
        const int krow = 16 * s + 8 * (ln >> 5);
        const int col  = 32 * n + (ln & 31);
        #pragma unroll
        for (int i = 0; i < 8; i += 2) {
            const float va = w1[(krow + i) * MDIM + col];
            const float vb = w1[(krow + i + 1) * MDIM + col];
            *(unsigned*)&w1f[f * 8 + i] = pkbf(va, vb);
        }
    }
    // ---- one-time: W2 fragments into registers ----
    short8 w2f[4][2];
    #pragma unroll
    for (int s = 0; s < 4; s++)
        #pragma unroll
        for (int n = 0; n < 2; n++) {
            FragU fu;
            #pragma unroll
            for (int i = 0; i < 8; i += 2) {
                const float va = w2[(16 * s + 8 * hi + i) * MDIM + 32 * n + r];
                const float vb = w2[(16 * s + 8 * hi + i + 1) * MDIM + 32 * n + r];
                fu.u[i >> 1] = pkbf(va, vb);
            }
            w2f[s][n] = fu.s;
        }
    const float b1c0 = b1[r], b1c1 = b1[32 + r];
    const float b2c0 = b2[r], b2c1 = b2[32 + r];
    __syncthreads();   // the only block barrier

    const int gwave = blockIdx.x * NW + wv;
    for (int q = gwave; q < QQ; q += nwaves) {
        const int t = times[q];
        int xb = 0, db = 0, mk = 0;
        if (lane < KK) {
            const int u   = uu[q * KK + lane];
            const int tau = tt[q * KK + lane];
            mk = mm[q * KK + lane];
            int d = (sign > 0) ? (t - tau) : (tau - t);
            d = d < 0 ? 0 : (d > WWINC ? WWINC : d);
            xb = u * (TSTEP * FF) + tau * FF;
            db = d * DDIM;
        }
        const unsigned long long bal = __ballot(mk != 0);   // bits 0..31 = edge masks
        const float cnt  = (float)__popcll(bal);
        const float cinv = 1.0f / fmaxf(cnt, 1.0f);
        const float has  = cnt > 0.0f ? 1.0f : 0.0f;
        // broadcast row-r metadata to both k-half lanes
        const int xbr = __shfl(xb, r, 64);
        const int dbr = __shfl(db, r, 64);
        const int mkr = __shfl(mk, r, 64);

        // ---- GEMM1 ----
        f32x16 acc0, acc1;
        #pragma unroll
        for (int i = 0; i < 16; i++) { acc0[i] = 0.0f; acc1[i] = 0.0f; }

        const float* xrow = x + xbr + 8 * hi;
        #pragma unroll 4
        for (int s = 0; s < 8; s++) {            // x part: k = 16s+8hi..+8
            float4 p0 = make_float4(0.f, 0.f, 0.f, 0.f), p1 = p0;
            if (mkr) {
                p0 = *(const float4*)(xrow + 16 * s);
                p1 = *(const float4*)(xrow + 16 * s + 4);
            }
            FragU fa;
            fa.u[0] = pkbf(p0.x, p0.y); fa.u[1] = pkbf(p0.z, p0.w);
            fa.u[2] = pkbf(p1.x, p1.y); fa.u[3] = pkbf(p1.z, p1.w);
            const short8 bf0 = *(const short8*)&w1f[(s * 2 + 0) * 512 + lane * 8];
            const short8 bf1 = *(const short8*)&w1f[(s * 2 + 1) * 512 + lane * 8];
            acc0 = __builtin_amdgcn_mfma_f32_32x32x16_bf16(fa.s, bf0, acc0, 0, 0, 0);
            acc1 = __builtin_amdgcn_mfma_f32_32x32x16_bf16(fa.s, bf1, acc1, 0, 0, 0);
        }
        {   // delta_emb part: k = 128+8hi..+8  (step s=8)
            float4 p0 = make_float4(0.f, 0.f, 0.f, 0.f), p1 = p0;
            if (mkr) {
                p0 = *(const float4*)(demb + dbr + 8 * hi);
                p1 = *(const float4*)(demb + dbr + 8 * hi + 4);
            }
            FragU fa;
            fa.u[0] = pkbf(p0.x, p0.y); fa.u[1] = pkbf(p0.z, p0.w);
            fa.u[2] = pkbf(p1.x, p1.y); fa.u[3] = pkbf(p1.z, p1.w);
            const short8 bf0 = *(const short8*)&w1f[(8 * 2 + 0) * 512 + lane * 8];
            const short8 bf1 = *(const short8*)&w1f[(8 * 2 + 1) * 512 + lane * 8];
            acc0 = __builtin_amdgcn_mfma_f32_32x32x16_bf16(fa.s, bf0, acc0, 0, 0, 0);
            acc1 = __builtin_amdgcn_mfma_f32_32x32x16_bf16(fa.s, bf1, acc1, 0, 0, 0);
        }

        // ---- epilogue 1: relu + bias, zero masked rows, write H (bf16) ----
        #pragma unroll
        for (int g = 0; g < 16; g++) {
            const int rr = (g & 3) + 8 * (g >> 2) + 4 * hi;     // edge row
            const float mrow = (float)((bal >> rr) & 1ull);
            const float h0 = fmaxf(acc0[g] + b1c0, 0.0f) * mrow;
            const float h1 = fmaxf(acc1[g] + b1c1, 0.0f) * mrow;
            Hs[wv][rr * HLD + r]      = (short)f2bf(h0);
            Hs[wv][rr * HLD + 32 + r] = (short)f2bf(h1);
        }

        // ---- GEMM2: H[32x64] @ W2[64x64] ----
        f32x16 c0, c1;
        #pragma unroll
        for (int i = 0; i < 16; i++) { c0[i] = 0.0f; c1[i] = 0.0f; }
        #pragma unroll
        for (int s = 0; s < 4; s++) {
            const short8 a = *(const short8*)&Hs[wv][r * HLD + 16 * s + 8 * hi];
            c0 = __builtin_amdgcn_mfma_f32_32x32x16_bf16(a, w2f[s][0], c0, 0, 0, 0);
            c1 = __builtin_amdgcn_mfma_f32_32x32x16_bf16(a, w2f[s][1], c1, 0, 0, 0);
        }

        // ---- epilogue 2: sum over edge rows (16 in-lane + partner half) ----
        float p0s = 0.0f, p1s = 0.0f;
        #pragma unroll
        for (int g = 0; g < 16; g++) { p0s += c0[g]; p1s += c1[g]; }
        p0s += __shfl_xor(p0s, 32, 64);
        p1s += __shfl_xor(p1s, 32, 64);
        const float outv = (hi ? p1s : p0s) * cinv + (hi ? b2c1 : b2c0) * has;
        mout[(size_t)q * MDIM + 32 * hi + r] = outv;
    }
}

// ---------------------------------------------------------------------------
// Kernel 2: combine (unchanged from round 1)
// ---------------------------------------------------------------------------
#define G2 16
#define FEATP 260
#define H1P   132

#define FMA8(cc, base) do { \
    const float4 wa_ = *(const float4*)(base); \
    const float4 wb_ = *(const float4*)((base) + 4); \
    acc[0] = fmaf((cc), wa_.x, acc[0]); acc[1] = fmaf((cc), wa_.y, acc[1]); \
    acc[2] = fmaf((cc), wa_.z, acc[2]); acc[3] = fmaf((cc), wa_.w, acc[3]); \
    acc[4] = fmaf((cc), wb_.x, acc[4]); acc[5] = fmaf((cc), wb_.y, acc[5]); \
    acc[6] = fmaf((cc), wb_.z, acc[6]); acc[7] = fmaf((cc), wb_.w, acc[7]); \
  } while (0)

__global__ __launch_bounds__(256, 2)
void combine_kernel(const float* __restrict__ x,
                    const float* __restrict__ cw1, const float* __restrict__ cb1,
                    const float* __restrict__ cw2, const float* __restrict__ cb2,
                    const int* __restrict__ node_ids, const int* __restrict__ times,
                    const float* __restrict__ min_ws, const float* __restrict__ mout_ws,
                    float* __restrict__ h_ws)
{
    __shared__ float feat[G2 * FEATP];
    __shared__ float h1b[G2 * H1P];
    __shared__ float cw2s[HDIM * HHDIM];
    __shared__ float cb1s[HDIM];
    __shared__ float cb2s[HHDIM];
    __shared__ int   xb[G2];

    const int tid = threadIdx.x;
    for (int i = tid; i < HDIM * HHDIM; i += 256) cw2s[i] = cw2[i];
    if (tid < HDIM)  cb1s[tid] = cb1[tid];
    if (tid < HHDIM) cb2s[tid] = cb2[tid];
    __syncthreads();

    const int g = tid >> 4;
    const int j = tid & 15;

    for (int qb = blockIdx.x * G2; qb < QQ; qb += gridDim.x * G2) {
        if (tid < G2) xb[tid] = node_ids[qb + tid] * (TSTEP * FF) + times[qb + tid] * FF;
        __syncthreads();
        for (int e = tid; e < G2 * 64; e += 256) {
            const int gg = e >> 6, c = e & 63;
            const int q = qb + gg;
            float4 v;
            if (c < 32)      v = *(const float4*)(x + xb[gg] + c * 4);
            else if (c < 48) v = *(const float4*)(min_ws  + (size_t)q * MDIM + (c - 32) * 4);
            else             v = *(const float4*)(mout_ws + (size_t)q * MDIM + (c - 48) * 4);
            *(float4*)(feat + gg * FEATP + c * 4) = v;
        }
        __syncthreads();

        float acc[8];
        {
            const float* fr = feat + g * FEATP;
            #pragma unroll
            for (int r2 = 0; r2 < 8; r2++) acc[r2] = cb1s[j * 8 + r2];
            #pragma unroll 4
            for (int i = 0; i < 2 * HDIM; i++) {
                const float f = fr[i];
                FMA8(f, cw1 + i * HDIM + j * 8);
            }
            #pragma unroll
            for (int r2 = 0; r2 < 8; r2++) acc[r2] = fmaxf(acc[r2], 0.0f);
        }
        *(float4*)(h1b + g * H1P + j * 8)     = make_float4(acc[0], acc[1], acc[2], acc[3]);
        *(float4*)(h1b + g * H1P + j * 8 + 4) = make_float4(acc[4], acc[5], acc[6], acc[7]);
        __syncthreads();

        {
            float a2[4];
            #pragma unroll
            for (int r2 = 0; r2 < 4; r2++) a2[r2] = cb2s[j * 4 + r2];
            const float* hr = h1b + g * H1P;
            #pragma unroll 4
            for (int i = 0; i < HDIM; i++) {
                const float hh = hr[i];
                const float4 w = *(const float4*)(cw2s + i * HHDIM + j * 4);
                a2[0] = fmaf(hh, w.x, a2[0]); a2[1] = fmaf(hh, w.y, a2[1]);
                a2[2] = fmaf(hh, w.z, a2[2]); a2[3] = fmaf(hh, w.w, a2[3]);
            }
            #pragma unroll
            for (int r2 = 0; r2 < 4; r2++) a2[r2] = fmaxf(a2[r2], 0.0f);
            *(float4*)(h_ws + (size_t)(qb + g) * HHDIM + j * 4) =
                make_float4(a2[0], a2[1], a2[2], a2[3]);
        }
        __syncthreads();
    }
}

// ---------------------------------------------------------------------------
// Kernel 3: scorer (unchanged from round 1)
// ---------------------------------------------------------------------------
#define G3 8
#define SFP 200

__global__ __launch_bounds__(256, 2)
void score_kernel(const float* __restrict__ h_ws, const float* __restrict__ dnorm,
                  const float* __restrict__ sw1, const float* __restrict__ sb1,
                  const float* __restrict__ sw2, const float* __restrict__ sb2,
                  float* __restrict__ out)
{
    __shared__ float featb[G3 * SFP];
    __shared__ float sw2s[HDIM];
    __shared__ float sb1s[HDIM];

    const int tid = threadIdx.x;
    if (tid < HDIM) { sw2s[tid] = sw2[tid]; sb1s[tid] = sb1[tid]; }
    __syncthreads();

    const int g = tid >> 5;
    const int j = tid & 31;

    for (int bb = blockIdx.x * G3; bb < BB; bb += gridDim.x * G3) {
        for (int e = tid; e < G3 * 48; e += 256) {
            const int gg = e / 48, c = e - gg * 48;
            *(float4*)(featb + gg * SFP + c * 4) =
                *(const float4*)(h_ws + (size_t)(bb + gg) * 192 + c * 4);
        }
        if (tid < G3) featb[tid * SFP + 192] = dnorm[bb + tid];
        __syncthreads();

        float a[4];
        #pragma unroll
        for (int r2 = 0; r2 < 4; r2++) a[r2] = sb1s[j * 4 + r2];
        const float* fr = featb + g * SFP;
        for (int i = 0; i < 193; i++) {
            const float f = fr[i];
            const float4 w = *(const float4*)(sw1 + i * HDIM + j * 4);
            a[0] = fmaf(f, w.x, a[0]); a[1] = fmaf(f, w.y, a[1]);
            a[2] = fmaf(f, w.z, a[2]); a[3] = fmaf(f, w.w, a[3]);
        }
        float p = 0.0f;
        #pragma unroll
        for (int r2 = 0; r2 < 4; r2++) p += fmaxf(a[r2], 0.0f) * sw2s[j * 4 + r2];
        for (int off = 16; off > 0; off >>= 1) p += __shfl_down(p, off, 32);
        if (j == 0) out[bb + g] = p + sb2[0];
        __syncthreads();
    }
}

// ---------------------------------------------------------------------------
extern "C" void kernel_launch(void* const* d_in, const int* in_sizes, int n_in,
                              void* d_out, int out_size, void* d_ws, size_t ws_size,
                              hipStream_t stream)
{
    const float* x     = (const float*)d_in[0];
    const float* dnorm = (const float*)d_in[1];
    const float* demb  = (const float*)d_in[2];
    const float* piw1  = (const float*)d_in[3];
    const float* pib1  = (const float*)d_in[4];
    const float* piw2  = (const float*)d_in[5];
    const float* pib2  = (const float*)d_in[6];
    const float* pow1  = (const float*)d_in[7];
    const float* pob1  = (const float*)d_in[8];
    const float* pow2  = (const float*)d_in[9];
    const float* pob2  = (const float*)d_in[10];
    const float* cw1   = (const float*)d_in[11];
    const float* cb1   = (const float*)d_in[12];
    const float* cw2   = (const float*)d_in[13];
    const float* cb2   = (const float*)d_in[14];
    const float* sw1   = (const float*)d_in[15];
    const float* sb1   = (const float*)d_in[16];
    const float* sw2   = (const float*)d_in[17];
    const float* sb2   = (const float*)d_in[18];
    const int* node_ids = (const int*)d_in[19];
    const int* times    = (const int*)d_in[20];
    const int* in_u     = (const int*)d_in[21];
    const int* in_tau   = (const int*)d_in[22];
    const int* in_mask  = (const int*)d_in[23];
    const int* out_u    = (const int*)d_in[24];
    const int* out_tau  = (const int*)d_in[25];
    const int* out_mask = (const int*)d_in[26];

    float* ws      = (float*)d_ws;
    float* min_ws  = ws;                         // QQ*64 floats
    float* mout_ws = ws + (size_t)QQ * MDIM;     // QQ*64 floats
    float* h_ws    = ws + (size_t)2 * QQ * MDIM; // QQ*64 floats
    float* out     = (float*)d_out;

    const int grid = 768;                 // 3 blocks/CU
    const int nwaves = grid * NW;         // 3072 -> exactly 8 q per wave

    agg_mfma_kernel<<<grid, 256, 0, stream>>>(x, demb, piw1, pib1, piw2, pib2,
                                              times, in_u, in_tau, in_mask,
                                              min_ws, 1, nwaves);
    agg_mfma_kernel<<<grid, 256, 0, stream>>>(x, demb, pow1, pob1, pow2, pob2,
                                              times, out_u, out_tau, out_mask,
                                              mout_ws, -1, nwaves);
    combine_kernel<<<512, 256, 0, stream>>>(x, cw1, cb1, cw2, cb2,
                                            node_ids, times, min_ws, mout_ws, h_ws);
    score_kernel<<<256, 256, 0, stream>>>(h_ws, dnorm, sw1, sb1, sw2, sb2, out);
}

// Round 3
// 919.123 us; speedup vs baseline: 2.2150x; 1.1189x over previous
//
#include <hip/hip_runtime.h>
#include <hip/hip_bf16.h>

// Problem constants (from reference)
#define NND   20000
#define TSTEP 64
#define FF    128
#define BB    8192
#define KK    32
#define QQ    (3*BB)      // 24576
#define WWINC 64
#define DDIM  16
#define MDIM  64          // msg dim
#define HDIM  128         // hidden dim
#define HHDIM 64          // h dim

typedef __attribute__((ext_vector_type(8)))  short short8;   // 8 bf16 (4 VGPRs)
typedef __attribute__((ext_vector_type(16))) float f32x16;   // 32x32 MFMA acc

union FragU { unsigned u[4]; short8 s; };

// fp32 -> bf16 (RNE), packed pair -> one dword
static __device__ __forceinline__ unsigned pkbf(float a, float b) {
    union { float f; unsigned u; } ua, ub; ua.f = a; ub.f = b;
    unsigned ra = (ua.u + 0x7FFFu + ((ua.u >> 16) & 1u)) >> 16;
    unsigned rb = (ub.u + 0x7FFFu + ((ub.u >> 16) & 1u)) >> 16;
    return (ra & 0xFFFFu) | (rb << 16);
}
static __device__ __forceinline__ short f2bf(float a) {
    union { float f; unsigned u; } v; v.f = a;
    return (short)((v.u + 0x7FFFu + ((v.u >> 16) & 1u)) >> 16);
}

// ---------------------------------------------------------------------------
// Weight pre-pack: cw1[256x128], cw2[128x64], sw1[rows 0..191][128] -> bf16
// B-fragment order. frag f, lane ln holds B[k=16s+8*(ln>>5)+i][col=32n+(ln&31)].
// 8192 threads, one 16B frag-slice each.
// ---------------------------------------------------------------------------
__global__ void pack_kernel(const float* __restrict__ cw1, const float* __restrict__ cw2,
                            const float* __restrict__ sw1,
                            short* __restrict__ cw1f, short* __restrict__ cw2f,
                            short* __restrict__ sw1f)
{
    const int gid = blockIdx.x * 256 + threadIdx.x;   // 0..8191
    const int ln  = gid & 63;
    const int f   = gid >> 6;                         // 0..127
    const int kr8 = 8 * (ln >> 5);
    const int c   = ln & 31;
    FragU v;
    if (f < 64) {            // cw1: 16 K-steps x 4 N-tiles
        const int s = f >> 2, n = f & 3;
        #pragma unroll
        for (int i = 0; i < 8; i += 2)
            v.u[i >> 1] = pkbf(cw1[(16*s + kr8 + i)     * HDIM + 32*n + c],
                               cw1[(16*s + kr8 + i + 1) * HDIM + 32*n + c]);
        *(short8*)&cw1f[f * 512 + ln * 8] = v.s;
    } else if (f < 80) {     // cw2: 8 K-steps x 2 N-tiles
        const int f2 = f - 64, s = f2 >> 1, n = f2 & 1;
        #pragma unroll
        for (int i = 0; i < 8; i += 2)
            v.u[i >> 1] = pkbf(cw2[(16*s + kr8 + i)     * HHDIM + 32*n + c],
                               cw2[(16*s + kr8 + i + 1) * HHDIM + 32*n + c]);
        *(short8*)&cw2f[f2 * 512 + ln * 8] = v.s;
    } else {                 // sw1 (rows 0..191): 12 K-steps x 4 N-tiles
        const int f3 = f - 80, s = f3 >> 2, n = f3 & 3;
        #pragma unroll
        for (int i = 0; i < 8; i += 2)
            v.u[i >> 1] = pkbf(sw1[(16*s + kr8 + i)     * HDIM + 32*n + c],
                               sw1[(16*s + kr8 + i + 1) * HDIM + 32*n + c]);
        *(short8*)&sw1f[f3 * 512 + ln * 8] = v.s;
    }
}

// ---------------------------------------------------------------------------
// MFMA edge aggregation (unchanged from round 2; ~144us each)
// ---------------------------------------------------------------------------
#define NW  4
#define HLD 72

__global__ __launch_bounds__(256, 3)
void agg_mfma_kernel(const float* __restrict__ x, const float* __restrict__ demb,
                     const float* __restrict__ w1, const float* __restrict__ b1,
                     const float* __restrict__ w2, const float* __restrict__ b2,
                     const int* __restrict__ times, const int* __restrict__ uu,
                     const int* __restrict__ tt, const int* __restrict__ mm,
                     float* __restrict__ mout, const int sign, const int nwaves)
{
    __shared__ short w1f[9 * 2 * 64 * 8];
    __shared__ short Hs[NW][KK * HLD];

    const int tid  = threadIdx.x;
    const int lane = tid & 63;
    const int wv   = tid >> 6;
    const int r    = lane & 31;
    const int hi   = lane >> 5;

    for (int f = tid; f < 9 * 2 * 64; f += 256) {
        const int ln = f & 63, sn = f >> 6, s = sn >> 1, n = sn & 1;
        const int krow = 16 * s + 8 * (ln >> 5);
        const int col  = 32 * n + (ln & 31);
        #pragma unroll
        for (int i = 0; i < 8; i += 2) {
            const float va = w1[(krow + i) * MDIM + col];
            const float vb = w1[(krow + i + 1) * MDIM + col];
            *(unsigned*)&w1f[f * 8 + i] = pkbf(va, vb);
        }
    }
    short8 w2f[4][2];
    #pragma unroll
    for (int s = 0; s < 4; s++)
        #pragma unroll
        for (int n = 0; n < 2; n++) {
            FragU fu;
            #pragma unroll
            for (int i = 0; i < 8; i += 2) {
                const float va = w2[(16 * s + 8 * hi + i) * MDIM + 32 * n + r];
                const float vb = w2[(16 * s + 8 * hi + i + 1) * MDIM + 32 * n + r];
                fu.u[i >> 1] = pkbf(va, vb);
            }
            w2f[s][n] = fu.s;
        }
    const float b1c0 = b1[r], b1c1 = b1[32 + r];
    const float b2c0 = b2[r], b2c1 = b2[32 + r];
    __syncthreads();

    const int gwave = blockIdx.x * NW + wv;
    for (int q = gwave; q < QQ; q += nwaves) {
        const int t = times[q];
        int xb = 0, db = 0, mk = 0;
        if (lane < KK) {
            const int u   = uu[q * KK + lane];
            const int tau = tt[q * KK + lane];
            mk = mm[q * KK + lane];
            int d = (sign > 0) ? (t - tau) : (tau - t);
            d = d < 0 ? 0 : (d > WWINC ? WWINC : d);
            xb = u * (TSTEP * FF) + tau * FF;
            db = d * DDIM;
        }
        const unsigned long long bal = __ballot(mk != 0);
        const float cnt  = (float)__popcll(bal);
        const float cinv = 1.0f / fmaxf(cnt, 1.0f);
        const float has  = cnt > 0.0f ? 1.0f : 0.0f;
        const int xbr = __shfl(xb, r, 64);
        const int dbr = __shfl(db, r, 64);
        const int mkr = __shfl(mk, r, 64);

        f32x16 acc0, acc1;
        #pragma unroll
        for (int i = 0; i < 16; i++) { acc0[i] = 0.0f; acc1[i] = 0.0f; }

        const float* xrow = x + xbr + 8 * hi;
        #pragma unroll 4
        for (int s = 0; s < 8; s++) {
            float4 p0 = make_float4(0.f, 0.f, 0.f, 0.f), p1 = p0;
            if (mkr) {
                p0 = *(const float4*)(xrow + 16 * s);
                p1 = *(const float4*)(xrow + 16 * s + 4);
            }
            FragU fa;
            fa.u[0] = pkbf(p0.x, p0.y); fa.u[1] = pkbf(p0.z, p0.w);
            fa.u[2] = pkbf(p1.x, p1.y); fa.u[3] = pkbf(p1.z, p1.w);
            const short8 bf0 = *(const short8*)&w1f[(s * 2 + 0) * 512 + lane * 8];
            const short8 bf1 = *(const short8*)&w1f[(s * 2 + 1) * 512 + lane * 8];
            acc0 = __builtin_amdgcn_mfma_f32_32x32x16_bf16(fa.s, bf0, acc0, 0, 0, 0);
            acc1 = __builtin_amdgcn_mfma_f32_32x32x16_bf16(fa.s, bf1, acc1, 0, 0, 0);
        }
        {
            float4 p0 = make_float4(0.f, 0.f, 0.f, 0.f), p1 = p0;
            if (mkr) {
                p0 = *(const float4*)(demb + dbr + 8 * hi);
                p1 = *(const float4*)(demb + dbr + 8 * hi + 4);
            }
            FragU fa;
            fa.u[0] = pkbf(p0.x, p0.y); fa.u[1] = pkbf(p0.z, p0.w);
            fa.u[2] = pkbf(p1.x, p1.y); fa.u[3] = pkbf(p1.z, p1.w);
            const short8 bf0 = *(const short8*)&w1f[(8 * 2 + 0) * 512 + lane * 8];
            const short8 bf1 = *(const short8*)&w1f[(8 * 2 + 1) * 512 + lane * 8];
            acc0 = __builtin_amdgcn_mfma_f32_32x32x16_bf16(fa.s, bf0, acc0, 0, 0, 0);
            acc1 = __builtin_amdgcn_mfma_f32_32x32x16_bf16(fa.s, bf1, acc1, 0, 0, 0);
        }

        #pragma unroll
        for (int g = 0; g < 16; g++) {
            const int rr = (g & 3) + 8 * (g >> 2) + 4 * hi;
            const float mrow = (float)((bal >> rr) & 1ull);
            const float h0 = fmaxf(acc0[g] + b1c0, 0.0f) * mrow;
            const float h1 = fmaxf(acc1[g] + b1c1, 0.0f) * mrow;
            Hs[wv][rr * HLD + r]      = f2bf(h0);
            Hs[wv][rr * HLD + 32 + r] = f2bf(h1);
        }

        f32x16 c0, c1;
        #pragma unroll
        for (int i = 0; i < 16; i++) { c0[i] = 0.0f; c1[i] = 0.0f; }
        #pragma unroll
        for (int s = 0; s < 4; s++) {
            const short8 a = *(const short8*)&Hs[wv][r * HLD + 16 * s + 8 * hi];
            c0 = __builtin_amdgcn_mfma_f32_32x32x16_bf16(a, w2f[s][0], c0, 0, 0, 0);
            c1 = __builtin_amdgcn_mfma_f32_32x32x16_bf16(a, w2f[s][1], c1, 0, 0, 0);
        }

        float p0s = 0.0f, p1s = 0.0f;
        #pragma unroll
        for (int g = 0; g < 16; g++) { p0s += c0[g]; p1s += c1[g]; }
        p0s += __shfl_xor(p0s, 32, 64);
        p1s += __shfl_xor(p1s, 32, 64);
        const float outv = (hi ? p1s : p0s) * cinv + (hi ? b2c1 : b2c0) * has;
        mout[(size_t)q * MDIM + 32 * hi + r] = outv;
    }
}

// ---------------------------------------------------------------------------
// MFMA combine: [Q,256] @ cw1 -> relu -> @ cw2 -> relu -> h_bf (bf16 [Q,64]).
// One 32-q tile per 64-thread block; B-frags read pre-packed from global
// (16B/lane coalesced, L2-hot); H transposed through per-block LDS.
// ---------------------------------------------------------------------------
#define HLD2 136   // H row stride in bf16 (272B, 16B-aligned, 4-way b128 reads)

__global__ __launch_bounds__(64, 2)
void combine_mfma(const float* __restrict__ x,
                  const int* __restrict__ node_ids, const int* __restrict__ times,
                  const float* __restrict__ min_ws, const float* __restrict__ mout_ws,
                  const short* __restrict__ cw1f, const float* __restrict__ cb1,
                  const short* __restrict__ cw2f, const float* __restrict__ cb2,
                  short* __restrict__ h_bf)
{
    __shared__ short Hs[KK * HLD2];
    const int lane = threadIdx.x & 63;
    const int r = lane & 31, hi = lane >> 5;
    const int qb = blockIdx.x * 32;
    const int q  = qb + r;
    const int xb = node_ids[q] * (TSTEP * FF) + times[q] * FF;

    f32x16 acc[4];
    #pragma unroll
    for (int n = 0; n < 4; n++)
        #pragma unroll
        for (int i = 0; i < 16; i++) acc[n][i] = 0.0f;

    // K 0..127: x_vt
    const float* xrow = x + xb + 8 * hi;
    #pragma unroll
    for (int s = 0; s < 8; s++) {
        const float4 p0 = *(const float4*)(xrow + 16 * s);
        const float4 p1 = *(const float4*)(xrow + 16 * s + 4);
        FragU fa;
        fa.u[0] = pkbf(p0.x, p0.y); fa.u[1] = pkbf(p0.z, p0.w);
        fa.u[2] = pkbf(p1.x, p1.y); fa.u[3] = pkbf(p1.z, p1.w);
        #pragma unroll
        for (int n = 0; n < 4; n++) {
            const short8 bf = *(const short8*)&cw1f[(s * 4 + n) * 512 + lane * 8];
            acc[n] = __builtin_amdgcn_mfma_f32_32x32x16_bf16(fa.s, bf, acc[n], 0, 0, 0);
        }
    }
    // K 128..191: m_in
    const float* mrow = min_ws + (size_t)q * MDIM + 8 * hi;
    #pragma unroll
    for (int s = 0; s < 4; s++) {
        const float4 p0 = *(const float4*)(mrow + 16 * s);
        const float4 p1 = *(const float4*)(mrow + 16 * s + 4);
        FragU fa;
        fa.u[0] = pkbf(p0.x, p0.y); fa.u[1] = pkbf(p0.z, p0.w);
        fa.u[2] = pkbf(p1.x, p1.y); fa.u[3] = pkbf(p1.z, p1.w);
        #pragma unroll
        for (int n = 0; n < 4; n++) {
            const short8 bf = *(const short8*)&cw1f[((s + 8) * 4 + n) * 512 + lane * 8];
            acc[n] = __builtin_amdgcn_mfma_f32_32x32x16_bf16(fa.s, bf, acc[n], 0, 0, 0);
        }
    }
    // K 192..255: m_out
    const float* orow = mout_ws + (size_t)q * MDIM + 8 * hi;
    #pragma unroll
    for (int s = 0; s < 4; s++) {
        const float4 p0 = *(const float4*)(orow + 16 * s);
        const float4 p1 = *(const float4*)(orow + 16 * s + 4);
        FragU fa;
        fa.u[0] = pkbf(p0.x, p0.y); fa.u[1] = pkbf(p0.z, p0.w);
        fa.u[2] = pkbf(p1.x, p1.y); fa.u[3] = pkbf(p1.z, p1.w);
        #pragma unroll
        for (int n = 0; n < 4; n++) {
            const short8 bf = *(const short8*)&cw1f[((s + 12) * 4 + n) * 512 + lane * 8];
            acc[n] = __builtin_amdgcn_mfma_f32_32x32x16_bf16(fa.s, bf, acc[n], 0, 0, 0);
        }
    }

    // epilogue 1: relu + bias -> H (bf16, LDS)
    #pragma unroll
    for (int n = 0; n < 4; n++) {
        const float bias = cb1[32 * n + r];
        #pragma unroll
        for (int g = 0; g < 16; g++) {
            const int rr = (g & 3) + 8 * (g >> 2) + 4 * hi;
            Hs[rr * HLD2 + 32 * n + r] = f2bf(fmaxf(acc[n][g] + bias, 0.0f));
        }
    }
    __syncthreads();

    // GEMM2: H[32x128] @ cw2[128x64]
    f32x16 c0, c1;
    #pragma unroll
    for (int i = 0; i < 16; i++) { c0[i] = 0.0f; c1[i] = 0.0f; }
    #pragma unroll
    for (int s = 0; s < 8; s++) {
        const short8 a = *(const short8*)&Hs[r * HLD2 + 16 * s + 8 * hi];
        const short8 b0 = *(const short8*)&cw2f[(s * 2 + 0) * 512 + lane * 8];
        const short8 b1v = *(const short8*)&cw2f[(s * 2 + 1) * 512 + lane * 8];
        c0 = __builtin_amdgcn_mfma_f32_32x32x16_bf16(a, b0, c0, 0, 0, 0);
        c1 = __builtin_amdgcn_mfma_f32_32x32x16_bf16(a, b1v, c1, 0, 0, 0);
    }
    const float bb0 = cb2[r], bb1 = cb2[32 + r];
    #pragma unroll
    for (int g = 0; g < 16; g++) {
        const int rr = (g & 3) + 8 * (g >> 2) + 4 * hi;
        h_bf[(size_t)(qb + rr) * HHDIM + r]      = f2bf(fmaxf(c0[g] + bb0, 0.0f));
        h_bf[(size_t)(qb + rr) * HHDIM + 32 + r] = f2bf(fmaxf(c1[g] + bb1, 0.0f));
    }
}

// ---------------------------------------------------------------------------
// MFMA scorer: [B,192] @ sw1[0:192] (bf16 MFMA) + fp32 rank-1 (d_norm col),
// relu, fp32 dot with sw2, shfl-reduce. One 32-b tile per 64-thread block.
// ---------------------------------------------------------------------------
__global__ __launch_bounds__(64, 2)
void score_mfma(const short* __restrict__ h_bf, const float* __restrict__ dnorm,
                const short* __restrict__ sw1f, const float* __restrict__ sw1,
                const float* __restrict__ sb1, const float* __restrict__ sw2,
                const float* __restrict__ sb2, float* __restrict__ out)
{
    const int lane = threadIdx.x & 63;
    const int r = lane & 31, hi = lane >> 5;
    const int bb = blockIdx.x * 32;

    f32x16 acc[4];
    #pragma unroll
    for (int n = 0; n < 4; n++)
        #pragma unroll
        for (int i = 0; i < 16; i++) acc[n][i] = 0.0f;

    const short* arow = h_bf + (size_t)(bb + r) * 192 + 8 * hi;
    #pragma unroll
    for (int s = 0; s < 12; s++) {
        const short8 a = *(const short8*)(arow + 16 * s);
        #pragma unroll
        for (int n = 0; n < 4; n++) {
            const short8 bf = *(const short8*)&sw1f[(s * 4 + n) * 512 + lane * 8];
            acc[n] = __builtin_amdgcn_mfma_f32_32x32x16_bf16(a, bf, acc[n], 0, 0, 0);
        }
    }

    float sb1c[4], swr[4], sw2c[4];
    #pragma unroll
    for (int n = 0; n < 4; n++) {
        sb1c[n] = sb1[32 * n + r];
        swr[n]  = sw1[192 * HDIM + 32 * n + r];   // d_norm row of sw1
        sw2c[n] = sw2[32 * n + r];
    }
    const float sb2v = sb2[0];

    #pragma unroll
    for (int g = 0; g < 16; g++) {
        const int rr = (g & 3) + 8 * (g >> 2) + 4 * hi;   // b-row (uniform per half)
        const float dn = dnorm[bb + rr];
        float p = 0.0f;
        #pragma unroll
        for (int n = 0; n < 4; n++)
            p += fmaxf(acc[n][g] + sb1c[n] + dn * swr[n], 0.0f) * sw2c[n];
        p += __shfl_xor(p, 1);  p += __shfl_xor(p, 2);  p += __shfl_xor(p, 4);
        p += __shfl_xor(p, 8);  p += __shfl_xor(p, 16);
        if (r == 0) out[bb + rr] = p + sb2v;
    }
}

// ---------------------------------------------------------------------------
extern "C" void kernel_launch(void* const* d_in, const int* in_sizes, int n_in,
                              void* d_out, int out_size, void* d_ws, size_t ws_size,
                              hipStream_t stream)
{
    const float* x     = (const float*)d_in[0];
    const float* dnorm = (const float*)d_in[1];
    const float* demb  = (const float*)d_in[2];
    const float* piw1  = (const float*)d_in[3];
    const float* pib1  = (const float*)d_in[4];
    const float* piw2  = (const float*)d_in[5];
    const float* pib2  = (const float*)d_in[6];
    const float* pow1  = (const float*)d_in[7];
    const float* pob1  = (const float*)d_in[8];
    const float* pow2  = (const float*)d_in[9];
    const float* pob2  = (const float*)d_in[10];
    const float* cw1   = (const float*)d_in[11];
    const float* cb1   = (const float*)d_in[12];
    const float* cw2   = (const float*)d_in[13];
    const float* cb2   = (const float*)d_in[14];
    const float* sw1   = (const float*)d_in[15];
    const float* sb1   = (const float*)d_in[16];
    const float* sw2   = (const float*)d_in[17];
    const float* sb2   = (const float*)d_in[18];
    const int* node_ids = (const int*)d_in[19];
    const int* times    = (const int*)d_in[20];
    const int* in_u     = (const int*)d_in[21];
    const int* in_tau   = (const int*)d_in[22];
    const int* in_mask  = (const int*)d_in[23];
    const int* out_u    = (const int*)d_in[24];
    const int* out_tau  = (const int*)d_in[25];
    const int* out_mask = (const int*)d_in[26];

    float* ws      = (float*)d_ws;
    float* min_ws  = ws;                          // QQ*64 floats
    float* mout_ws = ws + (size_t)QQ * MDIM;      // QQ*64 floats
    short* h_bf    = (short*)(ws + (size_t)2 * QQ * MDIM);   // BB*192 bf16
    short* wpack   = (short*)(ws + (size_t)2 * QQ * MDIM + (size_t)BB * 192 / 2);
    short* cw1f    = wpack;            // 64 frags * 512 = 32768 shorts
    short* cw2f    = wpack + 32768;    // 16 frags -> 8192
    short* sw1f    = wpack + 40960;    // 48 frags -> 24576
    float* out     = (float*)d_out;

    const int grid = 768;
    const int nwaves = grid * NW;      // 3072 waves -> 8 q per wave

    pack_kernel<<<32, 256, 0, stream>>>(cw1, cw2, sw1, cw1f, cw2f, sw1f);
    agg_mfma_kernel<<<grid, 256, 0, stream>>>(x, demb, piw1, pib1, piw2, pib2,
                                              times, in_u, in_tau, in_mask,
                                              min_ws, 1, nwaves);
    agg_mfma_kernel<<<grid, 256, 0, stream>>>(x, demb, pow1, pob1, pow2, pob2,
                                              times, out_u, out_tau, out_mask,
                                              mout_ws, -1, nwaves);
    combine_mfma<<<QQ / 32, 64, 0, stream>>>(x, node_ids, times, min_ws, mout_ws,
                                             cw1f, cb1, cw2f, cb2, h_bf);
    score_mfma<<<BB / 32, 64, 0, stream>>>(h_bf, dnorm, sw1f, sw1, sb1, sw2, sb2, out);
}